// Round 6
// baseline (10807.866 us; speedup 1.0000x reference)
//
#include <hip/hip_runtime.h>

typedef unsigned short u16;
typedef __attribute__((ext_vector_type(8))) __bf16 bf16x8;
typedef __attribute__((ext_vector_type(4))) float f32x4;

#define T_SEQ 256
#define N_B   1024
#define C_IN  128
#define H_DIM 512
#define NCLS  40
#define NT0   20
#define NT1   32
#define HSLOT (16*1024*32)   // u16 elems per hpack slot

union B8 { bf16x8 v; u16 s[8]; };

// ---------- bf16 split helpers ----------
__device__ __forceinline__ u16 f32_to_bf16_rne(float x) {
    unsigned u = __float_as_uint(x);
    unsigned rounding = 0x7FFFu + ((u >> 16) & 1u);
    return (u16)((u + rounding) >> 16);
}
__device__ __forceinline__ float bf16_to_f32(u16 h) {
    return __uint_as_float(((unsigned)h) << 16);
}
__device__ __forceinline__ void split2(float x, u16& hi, u16& lo) {
    u16 h = f32_to_bf16_rne(x);
    float hf = bf16_to_f32(h);
    u16 l = f32_to_bf16_rne(x - hf);
    hi = h; lo = l;
}
__device__ __forceinline__ float fast_sigmoid(float x) {
    return 1.0f / (1.0f + __expf(-x));
}
__device__ __forceinline__ float fast_tanh(float x) {
    return 1.0f - 2.0f / (__expf(2.0f * x) + 1.0f);
}

// ---------- prep: pack W into per-(ct,kt) fragment blocks ----------
// layout: idx = ((ct*NT + kt)*128 + r)*32 + k ; r = 4*jl + gate; ct = 32 hidden cols
__global__ void k_pack_w(const float* __restrict__ Wih, const float* __restrict__ Whh,
                         int KX, int NT, u16* __restrict__ hi, u16* __restrict__ lo) {
    size_t idx = (size_t)blockIdx.x * 256 + threadIdx.x;
    size_t total = (size_t)16 * NT * 128 * 32;
    if (idx >= total) return;
    int k = (int)(idx & 31);
    int r = (int)((idx >> 5) & 127);
    int rem = (int)(idx >> 12);
    int kt = rem % NT, ct = rem / NT;
    int gate = r & 3, jl = r >> 2;
    int srow = (gate << 9) + (ct << 5) + jl;
    int kg = (kt << 5) + k;
    float v = (kg < KX) ? Wih[(size_t)srow * KX + kg] : Whh[(size_t)srow * H_DIM + (kg - KX)];
    u16 h, l; split2(v, h, l);
    hi[idx] = h; lo[idx] = l;
}

// ---------- fragment bundle: wave tile 64 rows x 64 G'-cols ----------
struct Frag16 { bf16x8 ah[4], al[4], bh[4], bl[4]; };

__device__ __forceinline__ void load_frags(Frag16& F, int kt,
    const float* __restrict__ Xf32,
    const u16* __restrict__ xhi, const u16* __restrict__ xlo, int nxt,
    const u16* __restrict__ hhi, const u16* __restrict__ hlo,
    const u16* __restrict__ Whi, const u16* __restrict__ Wlo,
    int wbase, int n0, int wc, int quad, int lr)
{
    // B frags: dense 1KB/instr inside the (ct,kt) 8KB pack block
    #pragma unroll
    for (int j = 0; j < 4; j++) {
        size_t o = ((size_t)(wbase + kt) * 128 + wc + (j << 4) + lr) * 32 + (quad << 3);
        F.bh[j] = *(const bf16x8*)(Whi + o);
        F.bl[j] = *(const bf16x8*)(Wlo + o);
    }
    if (Xf32 != nullptr && kt < nxt) {
        // fp32 data slice, split in-register (only 4 of 20 k-tiles of L0)
        #pragma unroll
        for (int i = 0; i < 4; i++) {
            const float* p = Xf32 + (size_t)(n0 + (i << 4) + lr) * 32768 + (kt << 5) + (quad << 3);
            f32x4 x0 = *(const f32x4*)p;
            f32x4 x1 = *(const f32x4*)(p + 4);
            B8 hh, ll;
            #pragma unroll
            for (int e = 0; e < 4; e++) { u16 a, b; split2(x0[e], a, b); hh.s[e] = a; ll.s[e] = b; }
            #pragma unroll
            for (int e = 0; e < 4; e++) { u16 a, b; split2(x1[e], a, b); hh.s[4 + e] = a; ll.s[4 + e] = b; }
            F.ah[i] = hh.v; F.al[i] = ll.v;
        }
    } else {
        const u16 *ph, *pl; int kk;
        if (kt < nxt) { ph = xhi; pl = xlo; kk = kt; }
        else          { ph = hhi; pl = hlo; kk = kt - nxt; }
        #pragma unroll
        for (int i = 0; i < 4; i++) {
            size_t o = (((size_t)kk * 1024 + n0 + (i << 4) + lr) << 5) + (quad << 3);
            F.ah[i] = *(const bf16x8*)(ph + o);
            F.al[i] = *(const bf16x8*)(pl + o);
        }
    }
}

__device__ __forceinline__ void mfma48(const Frag16& F, f32x4 acc[4][4]) {
    #pragma unroll
    for (int i = 0; i < 4; i++)
        #pragma unroll
        for (int j = 0; j < 4; j++) {
            acc[i][j] = __builtin_amdgcn_mfma_f32_16x16x32_bf16(F.ah[i], F.bh[j], acc[i][j], 0, 0, 0);
            acc[i][j] = __builtin_amdgcn_mfma_f32_16x16x32_bf16(F.al[i], F.bh[j], acc[i][j], 0, 0, 0);
            acc[i][j] = __builtin_amdgcn_mfma_f32_16x16x32_bf16(F.ah[i], F.bl[j], acc[i][j], 0, 0, 0);
        }
}

// ---------- LSTM step tile: block = 128 threads (2 waves), 64 rows x 128 G'-cols ----------
__device__ __forceinline__ void lstm_tile_body(
    int blk,                                    // 0..255 within layer
    const float* __restrict__ Xf32,
    const u16* __restrict__ xhi, const u16* __restrict__ xlo, int nxt,
    const u16* __restrict__ hhi, const u16* __restrict__ hlo,
    const u16* __restrict__ Whi, const u16* __restrict__ Wlo, int NT,
    const float* __restrict__ bias, float* __restrict__ cbuf,
    u16* __restrict__ oHhi, u16* __restrict__ oHlo, float* __restrict__ oF32,
    float* Gs, float* biasT)
{
    // XCD swizzle: same-XCD blocks share 2 ct values -> W slice L2-resident
    int ct = ((blk & 7) << 1) | ((blk >> 3) & 1);   // 0..15 (32 hidden cols)
    int rt = blk >> 4;                              // 0..15 (64 batch rows)
    int n0 = rt << 6;

    int tid  = threadIdx.x;      // 0..127
    int w    = tid >> 6;
    int l    = tid & 63;
    int quad = l >> 4;
    int lr   = l & 15;
    int wc   = w << 6;           // 0 or 64

    biasT[tid] = bias[((tid & 3) << 9) + (ct << 5) + (tid >> 2)];

    int wbase = ct * NT;

    f32x4 acc[4][4];
    #pragma unroll
    for (int i = 0; i < 4; i++)
        #pragma unroll
        for (int j = 0; j < 4; j++)
            acc[i][j] = (f32x4){0.f, 0.f, 0.f, 0.f};

    // barrier-free K-loop, 2-deep register pipeline (NT is even: 20 or 32)
    Frag16 Fa, Fb;
    load_frags(Fa, 0, Xf32, xhi, xlo, nxt, hhi, hlo, Whi, Wlo, wbase, n0, wc, quad, lr);
    int tt = 0;
    for (; tt + 2 < NT; tt += 2) {
        load_frags(Fb, tt + 1, Xf32, xhi, xlo, nxt, hhi, hlo, Whi, Wlo, wbase, n0, wc, quad, lr);
        mfma48(Fa, acc);
        load_frags(Fa, tt + 2, Xf32, xhi, xlo, nxt, hhi, hlo, Whi, Wlo, wbase, n0, wc, quad, lr);
        mfma48(Fb, acc);
    }
    load_frags(Fb, NT - 1, Xf32, xhi, xlo, nxt, hhi, hlo, Whi, Wlo, wbase, n0, wc, quad, lr);
    mfma48(Fa, acc);
    mfma48(Fb, acc);

    // dump G' (64x128 fp32 = 32KB) to LDS; C/D layout: col = lane&15, row = quad*4 + reg
    #pragma unroll
    for (int i = 0; i < 4; i++)
        #pragma unroll
        for (int j = 0; j < 4; j++)
            #pragma unroll
            for (int r = 0; r < 4; r++)
                Gs[((i << 4) + (quad << 2) + r) * 128 + wc + (j << 4) + lr] = acc[i][j][r];
    __syncthreads();

    // epilogue: G' col = 4*jl + gate
    int jl = tid & 31;
    int r0 = tid >> 5;          // 0..3
    #pragma unroll
    for (int it = 0; it < 16; it++) {
        int row = r0 + (it << 2);          // 0..63
        f32x4 gv = *(const f32x4*)(Gs + row * 128 + (jl << 2));
        float gi = gv[0] + biasT[(jl << 2) + 0];
        float gf = gv[1] + biasT[(jl << 2) + 1];
        float gg = gv[2] + biasT[(jl << 2) + 2];
        float go = gv[3] + biasT[(jl << 2) + 3];
        float si = fast_sigmoid(gi);
        float sf = fast_sigmoid(gf);
        float so = fast_sigmoid(go);
        int n = n0 + row;
        int cidx = (n << 9) + (ct << 5) + jl;
        float cn = sf * cbuf[cidx] + si * fast_tanh(gg);
        cbuf[cidx] = cn;
        float h = so * fast_tanh(cn);
        u16 hh2, hl2; split2(h, hh2, hl2);
        size_t ho = (((size_t)ct * 1024 + n) << 5) + jl;
        oHhi[ho] = hh2; oHlo[ho] = hl2;
        if (oF32) oF32[cidx] = h;
    }
}

// blocks 0..255: L1(t-1); blocks 256..511: L0(t).  (ordering pairs 1 L1 + 1 L0 per CU)
__global__ __launch_bounds__(128) void k_lstm_pair(
    int t, const float* __restrict__ data,
    const u16* __restrict__ W0hi, const u16* __restrict__ W0lo,
    const u16* __restrict__ W1hi, const u16* __restrict__ W1lo,
    const float* __restrict__ b0, const float* __restrict__ b1,
    u16* __restrict__ h0hi, u16* __restrict__ h0lo,
    u16* __restrict__ h1hi, u16* __restrict__ h1lo,
    float* __restrict__ c0, float* __restrict__ c1,
    float* __restrict__ bfeat)
{
    __shared__ __align__(16) float Gs[64 * 128];
    __shared__ float biasT[128];
    int blk = blockIdx.x & 255;

    if (blockIdx.x < 256) {
        if (t == 0) return;
        int s = t - 1;
        const u16* xh = h0hi + (size_t)(s & 1) * HSLOT;
        const u16* xl = h0lo + (size_t)(s & 1) * HSLOT;
        const u16* hh = h1hi + (size_t)((s - 1) & 1) * HSLOT;
        const u16* hl = h1lo + (size_t)((s - 1) & 1) * HSLOT;
        u16* oh = h1hi + (size_t)(s & 1) * HSLOT;
        u16* ol = h1lo + (size_t)(s & 1) * HSLOT;
        lstm_tile_body(blk, nullptr, xh, xl, 16, hh, hl,
                       W1hi, W1lo, NT1, b1, c1, oh, ol,
                       (s == T_SEQ - 1) ? bfeat : nullptr, Gs, biasT);
    } else {
        if (t >= T_SEQ) return;
        const u16* hh = h0hi + (size_t)((t - 1) & 1) * HSLOT;
        const u16* hl = h0lo + (size_t)((t - 1) & 1) * HSLOT;
        u16* oh = h0hi + (size_t)(t & 1) * HSLOT;
        u16* ol = h0lo + (size_t)(t & 1) * HSLOT;
        lstm_tile_body(blk, data + (size_t)t * C_IN, nullptr, nullptr, 4,
                       hh, hl, W0hi, W0lo, NT0, b0, c0, oh, ol,
                       nullptr, Gs, biasT);
    }
}

// ---------- heads + losses ----------
__global__ __launch_bounds__(64) void k_head(
    const float* __restrict__ hfeat, const float* __restrict__ Wcls, const float* __restrict__ bcls,
    const float* __restrict__ Wbb, const float* __restrict__ bbb,
    const int* __restrict__ labels, const float* __restrict__ props,
    float* __restrict__ accum)
{
    __shared__ float hs[H_DIM];
    __shared__ float logits[NCLS];
    __shared__ float bb[2];
    int n = blockIdx.x, t = threadIdx.x;
    for (int k = t; k < H_DIM; k += 64) hs[k] = hfeat[((size_t)n << 9) + k];
    __syncthreads();
    if (t < NCLS) {
        float s = bcls[t];
        const float* w = Wcls + (size_t)t * H_DIM;
        for (int k = 0; k < H_DIM; k++) s += hs[k] * w[k];
        logits[t] = s;
    } else if (t < NCLS + 2) {
        int j = t - NCLS;
        float s = bbb[j];
        const float* w = Wbb + (size_t)j * H_DIM;
        for (int k = 0; k < H_DIM; k++) s += hs[k] * w[k];
        bb[j] = s;
    }
    __syncthreads();
    if (t == 0) {
        float m = logits[0]; int am = 0;
        for (int j = 1; j < NCLS; j++) if (logits[j] > m) { m = logits[j]; am = j; }
        float se = 0.f;
        for (int j = 0; j < NCLS; j++) se += expf(logits[j] - m);
        int lbl = labels[n * 2];
        float logp = logits[lbl] - m - logf(se);
        atomicAdd(&accum[0], -logp);
        if (am == lbl) atomicAdd(&accum[1], 1.0f);
        float s2 = 0.f;
        for (int j = 0; j < 2; j++) {
            float target = props[n * 2 + j] * (1.0f / 256.0f);
            float d = fabsf(bb[j] - target);
            s2 += (d < 1.f) ? 0.5f * d * d : d - 0.5f;
        }
        atomicAdd(&accum[2], s2);
    }
}

__global__ void k_final(const float* __restrict__ accum, float* __restrict__ out) {
    out[0] = (accum[0] * (1.0f / 1024.0f)) / (1.0f + accum[1]);
    out[1] = accum[2] * (10.0f / 2048.0f);
}

// ---------- launch ----------
extern "C" void kernel_launch(void* const* d_in, const int* in_sizes, int n_in,
                              void* d_out, int out_size, void* d_ws, size_t ws_size,
                              hipStream_t stream) {
    const float* data  = (const float*)d_in[0];
    const int*   labels= (const int*)d_in[1];
    const float* props = (const float*)d_in[2];
    const float* Wih0  = (const float*)d_in[3];
    const float* Whh0  = (const float*)d_in[4];
    const float* b0    = (const float*)d_in[5];
    const float* Wih1  = (const float*)d_in[6];
    const float* Whh1  = (const float*)d_in[7];
    const float* b1    = (const float*)d_in[8];
    const float* Wcls  = (const float*)d_in[9];
    const float* bcls  = (const float*)d_in[10];
    const float* Wbb   = (const float*)d_in[11];
    const float* bbb   = (const float*)d_in[12];
    float* out = (float*)d_out;

    char* ws = (char*)d_ws;
    size_t off = 0;
    auto alloc = [&](size_t bytes) -> void* {
        void* p = ws + off;
        off = (off + bytes + 255) & ~(size_t)255;
        return p;
    };
    const size_t NH = (size_t)N_B * H_DIM;
    const size_t W0E = (size_t)16 * NT0 * 128 * 32;
    const size_t W1E = (size_t)16 * NT1 * 128 * 32;

    u16* W0hi = (u16*)alloc(W0E * 2);
    u16* W0lo = (u16*)alloc(W0E * 2);
    u16* W1hi = (u16*)alloc(W1E * 2);
    u16* W1lo = (u16*)alloc(W1E * 2);
    u16* h0hi = (u16*)alloc(2 * (size_t)HSLOT * 2);
    u16* h0lo = (u16*)alloc(2 * (size_t)HSLOT * 2);
    u16* h1hi = (u16*)alloc(2 * (size_t)HSLOT * 2);
    u16* h1lo = (u16*)alloc(2 * (size_t)HSLOT * 2);
    float* c0   = (float*)alloc(NH * 4);
    float* c1   = (float*)alloc(NH * 4);
    float* bfeat= (float*)alloc(NH * 4);
    float* accum= (float*)alloc(4 * 4);

    k_pack_w<<<(int)(W0E / 256), 256, 0, stream>>>(Wih0, Whh0, C_IN, NT0, W0hi, W0lo);
    k_pack_w<<<(int)(W1E / 256), 256, 0, stream>>>(Wih1, Whh1, H_DIM, NT1, W1hi, W1lo);

    (void)hipMemsetAsync(h0hi + HSLOT, 0, (size_t)HSLOT * 2, stream);
    (void)hipMemsetAsync(h0lo + HSLOT, 0, (size_t)HSLOT * 2, stream);
    (void)hipMemsetAsync(h1hi + HSLOT, 0, (size_t)HSLOT * 2, stream);
    (void)hipMemsetAsync(h1lo + HSLOT, 0, (size_t)HSLOT * 2, stream);
    (void)hipMemsetAsync(c0, 0, NH * 4, stream);
    (void)hipMemsetAsync(c1, 0, NH * 4, stream);
    (void)hipMemsetAsync(accum, 0, 16, stream);

    for (int t = 0; t <= T_SEQ; t++) {
        k_lstm_pair<<<512, 128, 0, stream>>>(
            t, data, W0hi, W0lo, W1hi, W1lo, b0, b1,
            h0hi, h0lo, h1hi, h1lo, c0, c1, bfeat);
    }

    k_head<<<N_B, 64, 0, stream>>>(bfeat, Wcls, bcls, Wbb, bbb, labels, props, accum);
    k_final<<<1, 1, 0, stream>>>(accum, out);
}